// Round 16
// baseline (671.787 us; speedup 1.0000x reference)
//
#include <hip/hip_runtime.h>
#include <hip/hip_bf16.h>
#include <math.h>

#define EMB  2048
#define NH   16
#define HD   128
#define SEQ  2048
#define BATCH 2
#define MTOK (BATCH*SEQ)   // 4096 tokens

using bf16x8 = __attribute__((ext_vector_type(8))) __bf16;
using f32x4  = __attribute__((ext_vector_type(4))) float;

__device__ __forceinline__ unsigned short f2bf(float x) {
    unsigned int u = __float_as_uint(x);
    u += 0x7fffu + ((u >> 16) & 1u);   // round-to-nearest-even
    return (unsigned short)(u >> 16);
}
__device__ __forceinline__ float bf2f(unsigned int u16) {
    return __uint_as_float(u16 << 16);
}

__device__ __forceinline__ float gelu_exact(float x) {
    return 0.5f * x * (1.0f + erff(x * 0.70710678118654752f));
}

// ---------------- flat f32 -> bf16 convert (4 elems/thread) ----------------
__global__ __launch_bounds__(256) void k_conv(const float* __restrict__ in,
                                              unsigned short* __restrict__ out, int n4) {
    int i = blockIdx.x * 256 + threadIdx.x;
    if (i >= n4) return;
    float4 v = ((const float4*)in)[i];
    ushort4 o;
    o.x = f2bf(v.x); o.y = f2bf(v.y); o.z = f2bf(v.z); o.w = f2bf(v.w);
    ((ushort4*)out)[i] = o;
}

// ------------- W[K][N] f32 -> Wt[N][K] bf16 (tiled transpose) ---------------
__global__ __launch_bounds__(256) void k_transconv(const float* __restrict__ W,
                                                   unsigned short* __restrict__ Wt,
                                                   int K, int N) {
    __shared__ float t[32][33];
    int tx = threadIdx.x & 31, ty = threadIdx.x >> 5;   // 32 x 8
    int c0 = blockIdx.x * 32, r0 = blockIdx.y * 32;
    #pragma unroll
    for (int i = 0; i < 4; ++i)
        t[ty + i*8][tx] = W[(size_t)(r0 + ty + i*8) * N + c0 + tx];
    __syncthreads();
    #pragma unroll
    for (int i = 0; i < 4; ++i)
        Wt[(size_t)(c0 + ty + i*8) * K + r0 + tx] = f2bf(t[tx][ty + i*8]);
}

// ------------- 256x128 bf16 MFMA GEMM, 3-deep pipeline, 1 barrier/K-tile -----
// C = A[M,K] @ Bt[N,K]^T.  512 threads = 8 waves (4 wm x 2 wn), wave 64x64.
// BK=32; LDS = 3 buffers x (A 16KB + B 8KB) = 72 KB -> 2 blocks/CU.
// __launch_bounds__(512,4) -> VGPR ~56, NO SPILL.
// SINGLE barrier per K-tile (race-audited): at iter t, after gate+barrier all
// waves finished reading buf (t-1)%3 (their reads ended in iter t-1) -> stage
// tile t+2 into that buf immediately; its reader is iter t+2, protected by the
// entry gate vmcnt(3) (retires stage(t), keeps stage(t+1) in flight).
// bm-fast XCD-chunked raster; chunk-XOR swizzle chunk^=(row>>1)&3 both sides;
// T5 setprio.  ALL grids are integer multiples of 512 -- no tails.
// EPI: 2 = bf16 GELU(+bias); 5 = bf16 split-K partial (no bias);
//      7 = fused QK (C0=Q bf16, C1=K bf16; bias = bq||bk, 4096);
//      8 = V^T-scatter bf16 split-K partial (no bias)
template<int EPI, int NSPLIT>
__global__ __launch_bounds__(512, 4) void k_gemm5(const unsigned short* __restrict__ A,
                                                  const unsigned short* __restrict__ Bt,
                                                  const float* __restrict__ bias,
                                                  void* __restrict__ C0,
                                                  void* __restrict__ C1,
                                                  int M, int N, int Kred, int ldk) {
    __shared__ unsigned short As[3][256 * 32];
    __shared__ unsigned short Bs[3][128 * 32];
    const int tid = threadIdx.x, lane = tid & 63, wid = tid >> 6;
    const int la15 = lane & 15, g = lane >> 4;
    const int wm = wid >> 1, wn = wid & 1;              // 4 x 2 waves
    const int nmt = M >> 8, nnt = N >> 7;
    const int nblk = nmt * nnt * NSPLIT, cpx = nblk >> 3;
    const int swz = (blockIdx.x & 7) * cpx + (blockIdx.x >> 3);   // XCD-chunked
    const int bm = swz % nmt;                           // bm-fast (r11-proven)
    const int t2 = swz / nmt;
    const int bn = t2 % nnt, kk2 = t2 / nnt;
    const unsigned short* Ab = A  + (size_t)bm * 256 * ldk + (size_t)kk2 * Kred;
    const unsigned short* Bb = Bt + (size_t)bn * 128 * ldk + (size_t)kk2 * Kred;

    auto STAGE = [&](int ti, int bbuf) {
        const int kt = ti * 32;
        #pragma unroll
        for (int it = 0; it < 2; ++it) {               // A: 1024 chunks
            const int slot = it * 512 + tid;
            const int r = slot >> 2, pos = slot & 3;
            const unsigned short* ga = Ab + (size_t)r * ldk + kt
                                     + ((pos ^ ((r >> 1) & 3)) * 8);
            __builtin_amdgcn_global_load_lds(
                (const __attribute__((address_space(1))) void*)ga,
                (__attribute__((address_space(3))) void*)&As[bbuf][(it*512 + wid*64) * 8], 16, 0, 0);
        }
        {                                              // B: 512 chunks
            const int r = tid >> 2, pos = tid & 3;
            const unsigned short* gb = Bb + (size_t)r * ldk + kt
                                     + ((pos ^ ((r >> 1) & 3)) * 8);
            __builtin_amdgcn_global_load_lds(
                (const __attribute__((address_space(1))) void*)gb,
                (__attribute__((address_space(3))) void*)&Bs[bbuf][(size_t)wid * 64 * 8], 16, 0, 0);
        }
    };

    f32x4 acc[4][4] = {};
    const int NT = Kred >> 5;
    STAGE(0, 0);
    STAGE(1, 1);

    int cur = 0, stg = 2;                               // stg = (cur-1)%3 target
    for (int t = 0; t < NT; ++t) {
        // entry gate: retire stage(t); keep stage(t+1) in flight.
        if (t + 1 < NT) asm volatile("s_waitcnt vmcnt(3)" ::: "memory");
        else            asm volatile("s_waitcnt vmcnt(0)" ::: "memory");
        __builtin_amdgcn_s_barrier();                   // all waves past iter t-1 reads
        __builtin_amdgcn_sched_barrier(0);
        if (t + 2 < NT) STAGE(t + 2, stg);              // buf whose reads ended iter t-1
        __builtin_amdgcn_sched_barrier(0);

        bf16x8 af[4], bfr[4];
        #pragma unroll
        for (int mi = 0; mi < 4; ++mi) {
            const int r = wm*64 + mi*16 + la15;
            af[mi] = *(const bf16x8*)&As[cur][r*32 + ((g ^ ((r >> 1) & 3)) * 8)];
        }
        #pragma unroll
        for (int ni = 0; ni < 4; ++ni) {
            const int r = wn*64 + ni*16 + la15;
            bfr[ni] = *(const bf16x8*)&Bs[cur][r*32 + ((g ^ ((r >> 1) & 3)) * 8)];
        }
        __builtin_amdgcn_s_setprio(1);
        #pragma unroll
        for (int mi = 0; mi < 4; ++mi)
            #pragma unroll
            for (int ni = 0; ni < 4; ++ni)
                acc[mi][ni] = __builtin_amdgcn_mfma_f32_16x16x32_bf16(af[mi], bfr[ni], acc[mi][ni], 0, 0, 0);
        __builtin_amdgcn_s_setprio(0);
        __builtin_amdgcn_sched_barrier(0);
        stg = cur;
        cur = (cur == 2) ? 0 : cur + 1;
    }

    const int row0b = bm*256 + wm*64, col0 = bn*128 + wn*64;
    #pragma unroll
    for (int mi = 0; mi < 4; ++mi) {
        #pragma unroll
        for (int ni = 0; ni < 4; ++ni) {
            const int c = col0 + ni*16 + la15;
            const int r0 = row0b + mi*16 + g * 4;
            if (EPI == 5) {
                unsigned short* out = (unsigned short*)C0 + (size_t)kk2 * M * N;
                #pragma unroll
                for (int j = 0; j < 4; ++j)
                    out[(size_t)(r0+j) * N + c] = f2bf(acc[mi][ni][j]);
            } else if (EPI == 2) {
                const float bv = bias[c];
                #pragma unroll
                for (int j = 0; j < 4; ++j)
                    ((unsigned short*)C0)[(size_t)(r0+j) * N + c] = f2bf(gelu_exact(acc[mi][ni][j] + bv));
            } else if (EPI == 7) {  // fused QK: seg 0 -> Q, seg 1 -> K
                const float bv = bias[c];
                const int seg = c >> 11;
                if (seg == 0) {
                    #pragma unroll
                    for (int j = 0; j < 4; ++j)
                        ((unsigned short*)C0)[(size_t)(r0+j) * EMB + c] = f2bf(acc[mi][ni][j] + bv);
                } else {
                    #pragma unroll
                    for (int j = 0; j < 4; ++j)
                        ((unsigned short*)C1)[(size_t)(r0+j) * EMB + (c - 2048)] = f2bf(acc[mi][ni][j] + bv);
                }
            } else {  // EPI == 8: V^T-scatter bf16 split-K partial (no bias)
                const int hh = c >> 7, dd = c & 127;
                const int bb2 = r0 >> 11, s0 = r0 & 2047;
                unsigned short* out = (unsigned short*)C0 + (size_t)kk2 * ((size_t)MTOK * EMB);
                ushort4 uo;
                uo.x = f2bf(acc[mi][ni][0]); uo.y = f2bf(acc[mi][ni][1]);
                uo.z = f2bf(acc[mi][ni][2]); uo.w = f2bf(acc[mi][ni][3]);
                *(ushort4*)(out + ((size_t)((bb2*NH + hh)*HD + dd) * SEQ + s0)) = uo;
            }
        }
    }
}

// ------- combine V^T split-K bf16 partials + bias -> VT bf16 -----------------
__global__ __launch_bounds__(256) void k_vcomb(const unsigned short* __restrict__ a,
                                               const unsigned short* __restrict__ b,
                                               const float* __restrict__ bv,
                                               unsigned short* __restrict__ vt) {
    const int i8 = blockIdx.x * 256 + threadIdx.x;       // uint4 (8 bf16) index
    const float bias = bv[(i8 >> 8) & 2047];
    uint4 ua = ((const uint4*)a)[i8];
    uint4 ub = ((const uint4*)b)[i8];
    const unsigned int* pa = (const unsigned int*)&ua;
    const unsigned int* pb = (const unsigned int*)&ub;
    uint4 uo;
    unsigned int* po = (unsigned int*)&uo;
    #pragma unroll
    for (int i = 0; i < 4; ++i) {
        const unsigned short lo = f2bf(bf2f(pa[i] & 0xffffu) + bf2f(pb[i] & 0xffffu) + bias);
        const unsigned short hi = f2bf(bf2f(pa[i] >> 16)     + bf2f(pb[i] >> 16)     + bias);
        po[i] = (unsigned int)lo | ((unsigned int)hi << 16);
    }
    ((uint4*)vt)[i8] = uo;
}

// ------------- MFMA flash attention, KV-split partials (bf16, causal) -------
__global__ __launch_bounds__(256, 4) void k_attn_part(const unsigned short* __restrict__ Qb,
                                                      const unsigned short* __restrict__ Kb,
                                                      const unsigned short* __restrict__ VTb,
                                                      unsigned short* __restrict__ Opart,
                                                      float* __restrict__ Ml) {
    const int tid = threadIdx.x;
    const int lane = tid & 63, w = tid >> 6;
    const int g = lane >> 4, c = lane & 15;
    const int bid = blockIdx.x;
    const int swz = (bid & 7) * 512 + (bid >> 3);
    const int bh = swz >> 7;
    const int b = bh >> 4, h = bh & 15;
    const int rr = swz & 127;
    const int qt = rr >> 2, ks = rr & 3;
    const int nt = qt + 1;
    const int t0 = (nt * ks) >> 2, t1 = (nt * (ks + 1)) >> 2;
    const int qb = qt * 64 + w * 16;

    __shared__ unsigned short Ks[64 * 128];
    __shared__ unsigned short Vs[128 * 64];
    __shared__ unsigned short p_lds[4][16 * 64];

    bf16x8 qf[4];
    {
        const unsigned short* qrow = Qb + (size_t)(b*SEQ + qb + c) * EMB + h*HD;
        #pragma unroll
        for (int dch = 0; dch < 4; ++dch)
            qf[dch] = *(const bf16x8*)(qrow + dch*32 + g*8);
    }

    f32x4 o[8];
    #pragma unroll
    for (int ni = 0; ni < 8; ++ni) o[ni] = (f32x4){0.f, 0.f, 0.f, 0.f};
    float m_c = -1e30f, l_c = 0.f;

    const int q = qb + c;
    const int qmaxw = qb + 15;
    const unsigned short* Kbase = Kb  + (size_t)(b*SEQ) * EMB + h*HD;
    const unsigned short* Vbase = VTb + (size_t)((b*NH + h) * HD) * SEQ;
    const float scale = 0.08838834764831845f;
    char* pw = (char*)&p_lds[w][0];

    for (int ti = t0; ti < t1; ++ti) {
        const int tc = ti * 64;
        #pragma unroll
        for (int it = 0; it < 4; ++it) {
            const int cl = it * 256 + tid;
            const unsigned short* gk = Kbase + (size_t)(tc + (cl >> 4)) * EMB
                                     + (((cl & 15) ^ ((cl >> 4) & 7)) * 8);
            __builtin_amdgcn_global_load_lds(
                (const __attribute__((address_space(1))) void*)gk,
                (__attribute__((address_space(3))) void*)&Ks[(it*256 + w*64) * 8], 16, 0, 0);
            const unsigned short* gv = Vbase + (size_t)(cl >> 3) * SEQ + tc
                                     + (((cl & 7) ^ ((cl >> 3) & 7)) * 8);
            __builtin_amdgcn_global_load_lds(
                (const __attribute__((address_space(1))) void*)gv,
                (__attribute__((address_space(3))) void*)&Vs[(it*256 + w*64) * 8], 16, 0, 0);
        }
        __syncthreads();

        f32x4 sc[4];
        #pragma unroll
        for (int kt = 0; kt < 4; ++kt) {
            sc[kt] = (f32x4){0.f, 0.f, 0.f, 0.f};
            if (tc + kt*16 <= qmaxw) {
                #pragma unroll
                for (int dch = 0; dch < 4; ++dch) {
                    bf16x8 kf = *(const bf16x8*)&Ks[(kt*16 + c)*128 + (((dch*4 + g) ^ (c & 7)) * 8)];
                    sc[kt] = __builtin_amdgcn_mfma_f32_16x16x32_bf16(kf, qf[dch], sc[kt], 0, 0, 0);
                }
            }
        }
        float mx = -1e30f;
        #pragma unroll
        for (int kt = 0; kt < 4; ++kt)
            #pragma unroll
            for (int j = 0; j < 4; ++j) {
                const int key = tc + kt*16 + g*4 + j;
                const float s = (key <= q) ? sc[kt][j] * scale : -1e30f;
                mx = fmaxf(mx, s);
            }
        mx = fmaxf(mx, __shfl_xor(mx, 16));
        mx = fmaxf(mx, __shfl_xor(mx, 32));
        if (!__all(mx <= m_c + 8.f)) {
            const float mn = fmaxf(m_c, mx);
            const float corr = __expf(m_c - mn);
            l_c *= corr;
            m_c = mn;
            #pragma unroll
            for (int j = 0; j < 4; ++j) {
                const float cj = __shfl(corr, g*4 + j);
                #pragma unroll
                for (int ni = 0; ni < 8; ++ni) o[ni][j] *= cj;
            }
        }
        float ps = 0.f;
        #pragma unroll
        for (int kt = 0; kt < 4; ++kt) {
            float p[4];
            #pragma unroll
            for (int j = 0; j < 4; ++j) {
                const int key = tc + kt*16 + g*4 + j;
                const float s = (key <= q) ? sc[kt][j] * scale : -1e30f;
                p[j] = __expf(s - m_c);
                ps += p[j];
            }
            uint2 pk;
            pk.x = (unsigned int)f2bf(p[0]) | ((unsigned int)f2bf(p[1]) << 16);
            pk.y = (unsigned int)f2bf(p[2]) | ((unsigned int)f2bf(p[3]) << 16);
            const int byte = (c*128 + kt*32 + g*8) ^ ((c & 7) << 4);
            *(uint2*)(pw + byte) = pk;
        }
        ps += __shfl_xor(ps, 16);
        ps += __shfl_xor(ps, 32);
        l_c += ps;
        asm volatile("s_waitcnt lgkmcnt(0)" ::: "memory");
        __builtin_amdgcn_sched_barrier(0);
        #pragma unroll
        for (int kc = 0; kc < 2; ++kc) {
            if (tc + kc*32 <= qmaxw) {
                const int byte = (c*128 + kc*64 + g*16) ^ ((c & 7) << 4);
                bf16x8 pa = *(const bf16x8*)(pw + byte);
                #pragma unroll
                for (int ni = 0; ni < 8; ++ni) {
                    bf16x8 vf = *(const bf16x8*)&Vs[(ni*16 + c)*64 + (((kc*4 + g) ^ (c & 7)) * 8)];
                    o[ni] = __builtin_amdgcn_mfma_f32_16x16x32_bf16(pa, vf, o[ni], 0, 0, 0);
                }
            }
        }
        __syncthreads();
    }

    const int slot = ((b*NH + h) * 32 + qt) * 4 + ks;
    unsigned short* op = Opart + (size_t)slot * (64 * 128);
    #pragma unroll
    for (int ni = 0; ni < 8; ++ni)
        #pragma unroll
        for (int j = 0; j < 4; ++j)
            op[(size_t)(w*16 + g*4 + j) * 128 + ni*16 + c] = f2bf(o[ni][j]);
    if (lane < 16) {
        Ml[(size_t)slot * 128 +      w*16 + lane] = m_c;
        Ml[(size_t)slot * 128 + 64 + w*16 + lane] = l_c;
    }
}

// ------------- combine KV-split bf16 partials (4 slots) -> bf16 ctx ---------
__global__ __launch_bounds__(256) void k_attn_reduce(const unsigned short* __restrict__ Opart,
                                                     const float* __restrict__ Ml,
                                                     unsigned short* __restrict__ Ob) {
    const int qt = blockIdx.x, h = blockIdx.y, b = blockIdx.z;
    const int slot0 = ((b*NH + h) * 32 + qt) * 4;
    const int row = threadIdx.x >> 2;
    const int c0 = (threadIdx.x & 3) * 32;
    float M = -1e30f;
    #pragma unroll
    for (int s = 0; s < 4; ++s)
        M = fmaxf(M, Ml[(size_t)(slot0 + s) * 128 + row]);
    float L = 0.f;
    float wgt[4];
    #pragma unroll
    for (int s = 0; s < 4; ++s) {
        wgt[s] = __expf(Ml[(size_t)(slot0 + s) * 128 + row] - M);
        L += Ml[(size_t)(slot0 + s) * 128 + 64 + row] * wgt[s];
    }
    float acc[32];
    #pragma unroll
    for (int k = 0; k < 32; ++k) acc[k] = 0.f;
    #pragma unroll
    for (int s = 0; s < 4; ++s) {
        const unsigned short* op = Opart + ((size_t)(slot0 + s) * 64 + row) * 128 + c0;
        #pragma unroll
        for (int q4 = 0; q4 < 4; ++q4) {
            uint4 u = ((const uint4*)op)[q4];
            const unsigned int* pu = (const unsigned int*)&u;
            #pragma unroll
            for (int k = 0; k < 4; ++k) {
                acc[q4*8 + 2*k]     += bf2f(pu[k] & 0xffffu) * wgt[s];
                acc[q4*8 + 2*k + 1] += bf2f(pu[k] >> 16)     * wgt[s];
            }
        }
    }
    const float inv = 1.0f / L;
    unsigned short* orow = Ob + (size_t)(b*SEQ + qt*64 + row) * EMB + h*HD + c0;
    #pragma unroll
    for (int q4 = 0; q4 < 8; ++q4) {
        ushort4 u;
        u.x = f2bf(acc[q4*4+0] * inv); u.y = f2bf(acc[q4*4+1] * inv);
        u.z = f2bf(acc[q4*4+2] * inv); u.w = f2bf(acc[q4*4+3] * inv);
        ((ushort4*)orow)[q4] = u;
    }
}

// ------- row LayerNorm over 2048: x = X0+X1 (bf16) + bias (+resF f32 | resB bf16)
__global__ __launch_bounds__(256) void k_lnb(const unsigned short* __restrict__ X0,
                                             const unsigned short* __restrict__ X1,
                                             const float* __restrict__ bias,
                                             const float* __restrict__ resF,
                                             const unsigned short* __restrict__ resB,
                                             const float* __restrict__ g,
                                             const float* __restrict__ be,
                                             float* __restrict__ Of32,
                                             unsigned short* __restrict__ Obf16) {
    const int row = blockIdx.x, t = threadIdx.x;
    float v[8];
    {
        uint4 a = ((const uint4*)(X0 + (size_t)row * EMB))[t];
        uint4 b = ((const uint4*)(X1 + (size_t)row * EMB))[t];
        const unsigned int* pa = (const unsigned int*)&a;
        const unsigned int* pb = (const unsigned int*)&b;
        #pragma unroll
        for (int i = 0; i < 4; ++i) {
            v[2*i]   = bf2f(pa[i] & 0xffffu) + bf2f(pb[i] & 0xffffu);
            v[2*i+1] = bf2f(pa[i] >> 16)     + bf2f(pb[i] >> 16);
        }
    }
    {
        float4 b0 = ((const float4*)bias)[t*2], b1 = ((const float4*)bias)[t*2+1];
        v[0] += b0.x; v[1] += b0.y; v[2] += b0.z; v[3] += b0.w;
        v[4] += b1.x; v[5] += b1.y; v[6] += b1.z; v[7] += b1.w;
    }
    if (resF) {
        float4 r0 = ((const float4*)(resF + (size_t)row * EMB))[t*2];
        float4 r1 = ((const float4*)(resF + (size_t)row * EMB))[t*2+1];
        v[0] += r0.x; v[1] += r0.y; v[2] += r0.z; v[3] += r0.w;
        v[4] += r1.x; v[5] += r1.y; v[6] += r1.z; v[7] += r1.w;
    }
    if (resB) {
        uint4 r = ((const uint4*)(resB + (size_t)row * EMB))[t];
        const unsigned int* pr = (const unsigned int*)&r;
        #pragma unroll
        for (int i = 0; i < 4; ++i) {
            v[2*i]   += bf2f(pr[i] & 0xffffu);
            v[2*i+1] += bf2f(pr[i] >> 16);
        }
    }
    float s = 0.f, ss = 0.f;
    #pragma unroll
    for (int i = 0; i < 8; ++i) { s += v[i]; ss += v[i]*v[i]; }
    #pragma unroll
    for (int o = 32; o; o >>= 1) { s += __shfl_xor(s, o); ss += __shfl_xor(ss, o); }
    __shared__ float red[2][4];
    const int lane = t & 63, wid = t >> 6;
    if (lane == 0) { red[0][wid] = s; red[1][wid] = ss; }
    __syncthreads();
    s  = red[0][0] + red[0][1] + red[0][2] + red[0][3];
    ss = red[1][0] + red[1][1] + red[1][2] + red[1][3];
    const float mu = s * (1.0f / EMB);
    const float var = ss * (1.0f / EMB) - mu * mu;
    const float rs = rsqrtf(var + 1e-5f);
    float y[8];
    {
        float4 g0 = ((const float4*)g)[t*2],  g1v = ((const float4*)g)[t*2+1];
        float4 e0 = ((const float4*)be)[t*2], e1 = ((const float4*)be)[t*2+1];
        const float* pg0 = (const float*)&g0; const float* pg1 = (const float*)&g1v;
        const float* pe0 = (const float*)&e0; const float* pe1 = (const float*)&e1;
        #pragma unroll
        for (int i = 0; i < 4; ++i) {
            y[i]   = (v[i]   - mu) * rs * pg0[i] + pe0[i];
            y[i+4] = (v[i+4] - mu) * rs * pg1[i] + pe1[i];
        }
    }
    if (Of32) {
        float4 o0, o1;
        o0.x = y[0]; o0.y = y[1]; o0.z = y[2]; o0.w = y[3];
        o1.x = y[4]; o1.y = y[5]; o1.z = y[6]; o1.w = y[7];
        ((float4*)(Of32 + (size_t)row * EMB))[t*2]   = o0;
        ((float4*)(Of32 + (size_t)row * EMB))[t*2+1] = o1;
    }
    if (Obf16) {
        uint4 u;
        unsigned int* pu = (unsigned int*)&u;
        #pragma unroll
        for (int i = 0; i < 4; ++i)
            pu[i] = (unsigned int)f2bf(y[2*i]) | ((unsigned int)f2bf(y[2*i+1]) << 16);
        ((uint4*)(Obf16 + (size_t)row * EMB))[t] = u;
    }
}

extern "C" void kernel_launch(void* const* d_in, const int* in_sizes, int n_in,
                              void* d_out, int out_size, void* d_ws, size_t ws_size,
                              hipStream_t stream) {
    const float* emb = (const float*)d_in[0];
    const float* Wq  = (const float*)d_in[1];  const float* bq  = (const float*)d_in[2];
    const float* Wk  = (const float*)d_in[3];  const float* bk  = (const float*)d_in[4];
    const float* Wv  = (const float*)d_in[5];  const float* bv  = (const float*)d_in[6];
    const float* Wfc = (const float*)d_in[7];  const float* bfc = (const float*)d_in[8];
    const float* g1  = (const float*)d_in[9];  const float* be1 = (const float*)d_in[10];
    const float* W1  = (const float*)d_in[11]; const float* b1  = (const float*)d_in[12];
    const float* W2  = (const float*)d_in[13]; const float* b2  = (const float*)d_in[14];
    const float* g2  = (const float*)d_in[15]; const float* be2 = (const float*)d_in[16];

    // workspace layout (MiB offsets, lifetime-audited):
    //  [0,16)    aB: emb bf16 -> ctx bf16
    //  [16,32)   ln1B (after attn)
    //  [32,64)   WtB transposed weight (serial); [32,34) Ml during attn
    //  [64,128)  hB (W1 out); [64,80)/[80,96)/[96,112) Qb/Kb/VTb during attn
    //  [112,176) Opart bf16 (64 MiB) during attention only
    //  [176,208) pVT bf16 (V split-K partials, before attn) / pA+pB (after attn)
    //  [236,237) bias4 (bq||bk)
    char* ws = (char*)d_ws;
    unsigned short* aB   = (unsigned short*)(ws + (size_t)  0 * (1u<<20));
    unsigned short* ln1B = (unsigned short*)(ws + (size_t) 16 * (1u<<20));
    unsigned short* WtB  = (unsigned short*)(ws + (size_t) 32 * (1u<<20));
    float*          Ml   = (float*)         (ws + (size_t) 32 * (1u<<20));
    unsigned short* hB   = (unsigned short*)(ws + (size_t) 64 * (1u<<20));
    unsigned short* Qb   = (unsigned short*)(ws + (size_t) 64 * (1u<<20));
    unsigned short* Kb   = (unsigned short*)(ws + (size_t) 80 * (1u<<20));
    unsigned short* VTb  = (unsigned short*)(ws + (size_t) 96 * (1u<<20));
    unsigned short* Opart= (unsigned short*)(ws + (size_t)112 * (1u<<20));
    unsigned short* pA   = (unsigned short*)(ws + (size_t)176 * (1u<<20));
    unsigned short* pVT  = (unsigned short*)(ws + (size_t)176 * (1u<<20));
    float*          bias4= (float*)         (ws + (size_t)236 * (1u<<20));

    const dim3 blk(256);
    const dim3 blk2(512);
    const int n4 = MTOK * EMB / 4;
    const size_t PVT = (size_t)MTOK * EMB;   // one V-partial: 8.4M elems (16 MiB)

    // embeddings -> bf16; assemble fused QK bias (bq || bk)
    k_conv<<<dim3(n4 / 256), blk, 0, stream>>>(emb, aB, n4);
    hipMemcpyAsync(bias4,       bq, EMB*sizeof(float), hipMemcpyDeviceToDevice, stream);
    hipMemcpyAsync(bias4 + EMB, bk, EMB*sizeof(float), hipMemcpyDeviceToDevice, stream);

    // fused QK (N=4096, grid 512 balanced) + V split-K x2 (grid 512 balanced)
    k_transconv<<<dim3(EMB/32, EMB/32), blk, 0, stream>>>(Wq, WtB,             EMB, EMB);
    k_transconv<<<dim3(EMB/32, EMB/32), blk, 0, stream>>>(Wk, WtB + EMB*EMB,   EMB, EMB);
    k_transconv<<<dim3(EMB/32, EMB/32), blk, 0, stream>>>(Wv, WtB + 2*EMB*EMB, EMB, EMB);
    k_gemm5<7,1><<<dim3((MTOK/256)*(2*EMB/128)), blk2, 0, stream>>>(
        aB, WtB, bias4, Qb, Kb, MTOK, 2*EMB, EMB, EMB);
    k_gemm5<8,2><<<dim3((MTOK/256)*(EMB/128)*2), blk2, 0, stream>>>(
        aB, WtB + 2*EMB*EMB, nullptr, pVT, nullptr, MTOK, EMB, EMB/2, EMB);
    k_vcomb<<<dim3((int)(PVT/8/256)), blk, 0, stream>>>(pVT, pVT + PVT, bv, VTb);

    // KV-split MFMA flash attention -> bf16 partials -> ctx bf16 (overwrites aB)
    k_attn_part<<<dim3(4096), blk, 0, stream>>>(Qb, Kb, VTb, Opart, Ml);
    k_attn_reduce<<<dim3(SEQ/64, NH, BATCH), blk, 0, stream>>>(Opart, Ml, aB);

    // Wfc split-K x2 -> pA/pB bf16; LN1 fuses +bfc+emb -> ln1B only
    k_transconv<<<dim3(EMB/32, EMB/32), blk, 0, stream>>>(Wfc, WtB, EMB, EMB);
    k_gemm5<5,2><<<dim3((MTOK/256)*(EMB/128)*2), blk2, 0, stream>>>(
        aB, WtB, nullptr, pA, nullptr, MTOK, EMB, EMB/2, EMB);
    k_lnb<<<dim3(MTOK), blk, 0, stream>>>(pA, pA + (size_t)MTOK*EMB, bfc, emb, nullptr,
                                          g1, be1, nullptr, ln1B);

    // h = gelu(ln1 @ W1 + b1) -> hB
    k_transconv<<<dim3(4*EMB/32, EMB/32), blk, 0, stream>>>(W1, WtB, EMB, 4*EMB);
    k_gemm5<2,1><<<dim3((MTOK/256)*(4*EMB/128)), blk2, 0, stream>>>(
        ln1B, WtB, b1, hB, nullptr, MTOK, 4*EMB, EMB, EMB);

    // W2 split-K x2 -> pA/pB bf16; LN2 fuses +b2+ln1B -> d_out (f32)
    k_transconv<<<dim3(EMB/32, (4*EMB)/32), blk, 0, stream>>>(W2, WtB, 4*EMB, EMB);
    k_gemm5<5,2><<<dim3((MTOK/256)*(EMB/128)*2), blk2, 0, stream>>>(
        hB, WtB, nullptr, pA, nullptr, MTOK, EMB, 2*EMB, 4*EMB);
    k_lnb<<<dim3(MTOK), blk, 0, stream>>>(pA, pA + (size_t)MTOK*EMB, b2, nullptr, ln1B,
                                          g2, be2, (float*)d_out, nullptr);
}

// Round 17
// 656.143 us; speedup vs baseline: 1.0238x; 1.0238x over previous
//
#include <hip/hip_runtime.h>
#include <hip/hip_bf16.h>
#include <math.h>

#define EMB  2048
#define NH   16
#define HD   128
#define SEQ  2048
#define BATCH 2
#define MTOK (BATCH*SEQ)   // 4096 tokens

using bf16x8 = __attribute__((ext_vector_type(8))) __bf16;
using f32x4  = __attribute__((ext_vector_type(4))) float;

__device__ __forceinline__ unsigned short f2bf(float x) {
    unsigned int u = __float_as_uint(x);
    u += 0x7fffu + ((u >> 16) & 1u);   // round-to-nearest-even
    return (unsigned short)(u >> 16);
}
__device__ __forceinline__ float bf2f(unsigned int u16) {
    return __uint_as_float(u16 << 16);
}

__device__ __forceinline__ float gelu_exact(float x) {
    return 0.5f * x * (1.0f + erff(x * 0.70710678118654752f));
}

// ---------------- flat f32 -> bf16 convert (4 elems/thread) ----------------
__global__ __launch_bounds__(256) void k_conv(const float* __restrict__ in,
                                              unsigned short* __restrict__ out, int n4) {
    int i = blockIdx.x * 256 + threadIdx.x;
    if (i >= n4) return;
    float4 v = ((const float4*)in)[i];
    ushort4 o;
    o.x = f2bf(v.x); o.y = f2bf(v.y); o.z = f2bf(v.z); o.w = f2bf(v.w);
    ((ushort4*)out)[i] = o;
}

// ------------- W[K][N] f32 -> Wt[N][K] bf16 (tiled transpose) ---------------
__global__ __launch_bounds__(256) void k_transconv(const float* __restrict__ W,
                                                   unsigned short* __restrict__ Wt,
                                                   int K, int N) {
    __shared__ float t[32][33];
    int tx = threadIdx.x & 31, ty = threadIdx.x >> 5;   // 32 x 8
    int c0 = blockIdx.x * 32, r0 = blockIdx.y * 32;
    #pragma unroll
    for (int i = 0; i < 4; ++i)
        t[ty + i*8][tx] = W[(size_t)(r0 + ty + i*8) * N + c0 + tx];
    __syncthreads();
    #pragma unroll
    for (int i = 0; i < 4; ++i)
        Wt[(size_t)(c0 + ty + i*8) * K + r0 + tx] = f2bf(t[tx][ty + i*8]);
}

// ------------- 256x128 bf16 MFMA GEMM, 3-deep pipeline -----------------------
// C = A[M,K] @ Bt[N,K]^T.  512 threads = 8 waves (4 wm x 2 wn), wave 64x64.
// BK=32; LDS = 3 buffers x (A 16KB + B 8KB) = 72 KB.  __launch_bounds__(512,4)
// -> VGPR ~56, NO SPILL.  Entry gate vmcnt(3) steady (stage t+1 in flight),
// degrading to 0 in the tail (round-15 measured-best loop).
// NEW: 2-D chunk-tiled XCD rasterization.  Per XCD: ncol = nnt*NSPLIT/8
// columns, iterated in groups of 4 bm x ncol columns -> A working set per
// group = 4 x 1-2 MB (fits the 4 MB XCD L2); B streams once per group from
// L3.  bm-fast cycled ALL 16 A-panels (16 MB) per column -> L2 thrash
// (FETCH 150 MB vs ~48 ideal); bn-fast mirrored it on B (r13: 271 MB).
// Chunk-XOR swizzle chunk^=(row>>1)&3 both sides; T5 setprio.
// ALL grids are integer multiples of 512 (2 blocks/CU rounds) -- no tails.
// EPI: 2 = bf16 GELU(+bias); 5 = bf16 split-K partial (no bias);
//      7 = fused QK (C0=Q bf16, C1=K bf16; bias = bq||bk, 4096);
//      8 = V^T-scatter bf16 split-K partial (no bias)
template<int EPI, int NSPLIT>
__global__ __launch_bounds__(512, 4) void k_gemm5(const unsigned short* __restrict__ A,
                                                  const unsigned short* __restrict__ Bt,
                                                  const float* __restrict__ bias,
                                                  void* __restrict__ C0,
                                                  void* __restrict__ C1,
                                                  int M, int N, int Kred, int ldk) {
    __shared__ unsigned short As[3][256 * 32];
    __shared__ unsigned short Bs[3][128 * 32];
    const int tid = threadIdx.x, lane = tid & 63, wid = tid >> 6;
    const int la15 = lane & 15, g = lane >> 4;
    const int wm = wid >> 1, wn = wid & 1;              // 4 x 2 waves
    const int nmt = M >> 8, nnt = N >> 7;
    // 2-D chunk-tiled rasterization (bijective for all launch shapes):
    //   xcd = bid & 7; i = bid >> 3 in [0, 16*ncol)
    //   group bmg = i / (4*ncol); within group: bm = bmg*4 + (j&3),
    //   column colg = xcd*ncol + (j>>2);  bn = colg % nnt, kk2 = colg / nnt.
    const int ncol = (nnt * NSPLIT) >> 3;               // columns per XCD (4 or 8)
    const int xcd = blockIdx.x & 7;
    const int i4 = blockIdx.x >> 3;
    const int bmg = i4 / (ncol << 2);
    const int j4 = i4 - bmg * (ncol << 2);
    const int bm = (bmg << 2) + (j4 & 3);
    const int colg = xcd * ncol + (j4 >> 2);
    const int bn = colg % nnt, kk2 = colg / nnt;
    const unsigned short* Ab = A  + (size_t)bm * 256 * ldk + (size_t)kk2 * Kred;
    const unsigned short* Bb = Bt + (size_t)bn * 128 * ldk + (size_t)kk2 * Kred;

    auto STAGE = [&](int ti, int bbuf) {
        const int kt = ti * 32;
        #pragma unroll
        for (int it = 0; it < 2; ++it) {               // A: 1024 chunks
            const int slot = it * 512 + tid;
            const int r = slot >> 2, pos = slot & 3;
            const unsigned short* ga = Ab + (size_t)r * ldk + kt
                                     + ((pos ^ ((r >> 1) & 3)) * 8);
            __builtin_amdgcn_global_load_lds(
                (const __attribute__((address_space(1))) void*)ga,
                (__attribute__((address_space(3))) void*)&As[bbuf][(it*512 + wid*64) * 8], 16, 0, 0);
        }
        {                                              // B: 512 chunks
            const int r = tid >> 2, pos = tid & 3;
            const unsigned short* gb = Bb + (size_t)r * ldk + kt
                                     + ((pos ^ ((r >> 1) & 3)) * 8);
            __builtin_amdgcn_global_load_lds(
                (const __attribute__((address_space(1))) void*)gb,
                (__attribute__((address_space(3))) void*)&Bs[bbuf][(size_t)wid * 64 * 8], 16, 0, 0);
        }
    };

    f32x4 acc[4][4] = {};
    const int NT = Kred >> 5;
    STAGE(0, 0);
    STAGE(1, 1);
    STAGE(2, 2);

    int cur = 0;
    for (int t = 0; t < NT; ++t) {
        // entry gate: retire stage(t); keep stages t+1, t+2 in flight.
        if (t + 2 < NT)      asm volatile("s_waitcnt vmcnt(6)" ::: "memory");
        else if (t + 1 < NT) asm volatile("s_waitcnt vmcnt(3)" ::: "memory");
        else                 asm volatile("s_waitcnt vmcnt(0)" ::: "memory");
        __builtin_amdgcn_s_barrier();
        __builtin_amdgcn_sched_barrier(0);

        bf16x8 af[4], bfr[4];
        #pragma unroll
        for (int mi = 0; mi < 4; ++mi) {
            const int r = wm*64 + mi*16 + la15;
            af[mi] = *(const bf16x8*)&As[cur][r*32 + ((g ^ ((r >> 1) & 3)) * 8)];
        }
        #pragma unroll
        for (int ni = 0; ni < 4; ++ni) {
            const int r = wn*64 + ni*16 + la15;
            bfr[ni] = *(const bf16x8*)&Bs[cur][r*32 + ((g ^ ((r >> 1) & 3)) * 8)];
        }
        __builtin_amdgcn_s_setprio(1);
        #pragma unroll
        for (int mi = 0; mi < 4; ++mi)
            #pragma unroll
            for (int ni = 0; ni < 4; ++ni)
                acc[mi][ni] = __builtin_amdgcn_mfma_f32_16x16x32_bf16(af[mi], bfr[ni], acc[mi][ni], 0, 0, 0);
        __builtin_amdgcn_s_setprio(0);
        __builtin_amdgcn_sched_barrier(0);
        __builtin_amdgcn_s_barrier();                   // all waves done reading buf cur
        __builtin_amdgcn_sched_barrier(0);
        if (t + 3 < NT) STAGE(t + 3, cur);              // (t+3)%3 == cur
        cur = (cur == 2) ? 0 : cur + 1;
    }

    const int row0b = bm*256 + wm*64, col0 = bn*128 + wn*64;
    #pragma unroll
    for (int mi = 0; mi < 4; ++mi) {
        #pragma unroll
        for (int ni = 0; ni < 4; ++ni) {
            const int c = col0 + ni*16 + la15;
            const int r0 = row0b + mi*16 + g * 4;
            if (EPI == 5) {
                unsigned short* out = (unsigned short*)C0 + (size_t)kk2 * M * N;
                #pragma unroll
                for (int j = 0; j < 4; ++j)
                    out[(size_t)(r0+j) * N + c] = f2bf(acc[mi][ni][j]);
            } else if (EPI == 2) {
                const float bv = bias[c];
                #pragma unroll
                for (int j = 0; j < 4; ++j)
                    ((unsigned short*)C0)[(size_t)(r0+j) * N + c] = f2bf(gelu_exact(acc[mi][ni][j] + bv));
            } else if (EPI == 7) {  // fused QK: seg 0 -> Q, seg 1 -> K
                const float bv = bias[c];
                const int seg = c >> 11;
                if (seg == 0) {
                    #pragma unroll
                    for (int j = 0; j < 4; ++j)
                        ((unsigned short*)C0)[(size_t)(r0+j) * EMB + c] = f2bf(acc[mi][ni][j] + bv);
                } else {
                    #pragma unroll
                    for (int j = 0; j < 4; ++j)
                        ((unsigned short*)C1)[(size_t)(r0+j) * EMB + (c - 2048)] = f2bf(acc[mi][ni][j] + bv);
                }
            } else {  // EPI == 8: V^T-scatter bf16 split-K partial (no bias)
                const int hh = c >> 7, dd = c & 127;
                const int bb2 = r0 >> 11, s0 = r0 & 2047;
                unsigned short* out = (unsigned short*)C0 + (size_t)kk2 * ((size_t)MTOK * EMB);
                ushort4 uo;
                uo.x = f2bf(acc[mi][ni][0]); uo.y = f2bf(acc[mi][ni][1]);
                uo.z = f2bf(acc[mi][ni][2]); uo.w = f2bf(acc[mi][ni][3]);
                *(ushort4*)(out + ((size_t)((bb2*NH + hh)*HD + dd) * SEQ + s0)) = uo;
            }
        }
    }
}

// ------- combine V^T split-K bf16 partials + bias -> VT bf16 -----------------
__global__ __launch_bounds__(256) void k_vcomb(const unsigned short* __restrict__ a,
                                               const unsigned short* __restrict__ b,
                                               const float* __restrict__ bv,
                                               unsigned short* __restrict__ vt) {
    const int i8 = blockIdx.x * 256 + threadIdx.x;       // uint4 (8 bf16) index
    const float bias = bv[(i8 >> 8) & 2047];
    uint4 ua = ((const uint4*)a)[i8];
    uint4 ub = ((const uint4*)b)[i8];
    const unsigned int* pa = (const unsigned int*)&ua;
    const unsigned int* pb = (const unsigned int*)&ub;
    uint4 uo;
    unsigned int* po = (unsigned int*)&uo;
    #pragma unroll
    for (int i = 0; i < 4; ++i) {
        const unsigned short lo = f2bf(bf2f(pa[i] & 0xffffu) + bf2f(pb[i] & 0xffffu) + bias);
        const unsigned short hi = f2bf(bf2f(pa[i] >> 16)     + bf2f(pb[i] >> 16)     + bias);
        po[i] = (unsigned int)lo | ((unsigned int)hi << 16);
    }
    ((uint4*)vt)[i8] = uo;
}

// ------------- MFMA flash attention, KV-split partials (bf16, causal) -------
__global__ __launch_bounds__(256, 4) void k_attn_part(const unsigned short* __restrict__ Qb,
                                                      const unsigned short* __restrict__ Kb,
                                                      const unsigned short* __restrict__ VTb,
                                                      unsigned short* __restrict__ Opart,
                                                      float* __restrict__ Ml) {
    const int tid = threadIdx.x;
    const int lane = tid & 63, w = tid >> 6;
    const int g = lane >> 4, c = lane & 15;
    const int bid = blockIdx.x;
    const int swz = (bid & 7) * 512 + (bid >> 3);
    const int bh = swz >> 7;
    const int b = bh >> 4, h = bh & 15;
    const int rr = swz & 127;
    const int qt = rr >> 2, ks = rr & 3;
    const int nt = qt + 1;
    const int t0 = (nt * ks) >> 2, t1 = (nt * (ks + 1)) >> 2;
    const int qb = qt * 64 + w * 16;

    __shared__ unsigned short Ks[64 * 128];
    __shared__ unsigned short Vs[128 * 64];
    __shared__ unsigned short p_lds[4][16 * 64];

    bf16x8 qf[4];
    {
        const unsigned short* qrow = Qb + (size_t)(b*SEQ + qb + c) * EMB + h*HD;
        #pragma unroll
        for (int dch = 0; dch < 4; ++dch)
            qf[dch] = *(const bf16x8*)(qrow + dch*32 + g*8);
    }

    f32x4 o[8];
    #pragma unroll
    for (int ni = 0; ni < 8; ++ni) o[ni] = (f32x4){0.f, 0.f, 0.f, 0.f};
    float m_c = -1e30f, l_c = 0.f;

    const int q = qb + c;
    const int qmaxw = qb + 15;
    const unsigned short* Kbase = Kb  + (size_t)(b*SEQ) * EMB + h*HD;
    const unsigned short* Vbase = VTb + (size_t)((b*NH + h) * HD) * SEQ;
    const float scale = 0.08838834764831845f;
    char* pw = (char*)&p_lds[w][0];

    for (int ti = t0; ti < t1; ++ti) {
        const int tc = ti * 64;
        #pragma unroll
        for (int it = 0; it < 4; ++it) {
            const int cl = it * 256 + tid;
            const unsigned short* gk = Kbase + (size_t)(tc + (cl >> 4)) * EMB
                                     + (((cl & 15) ^ ((cl >> 4) & 7)) * 8);
            __builtin_amdgcn_global_load_lds(
                (const __attribute__((address_space(1))) void*)gk,
                (__attribute__((address_space(3))) void*)&Ks[(it*256 + w*64) * 8], 16, 0, 0);
            const unsigned short* gv = Vbase + (size_t)(cl >> 3) * SEQ + tc
                                     + (((cl & 7) ^ ((cl >> 3) & 7)) * 8);
            __builtin_amdgcn_global_load_lds(
                (const __attribute__((address_space(1))) void*)gv,
                (__attribute__((address_space(3))) void*)&Vs[(it*256 + w*64) * 8], 16, 0, 0);
        }
        __syncthreads();

        f32x4 sc[4];
        #pragma unroll
        for (int kt = 0; kt < 4; ++kt) {
            sc[kt] = (f32x4){0.f, 0.f, 0.f, 0.f};
            if (tc + kt*16 <= qmaxw) {
                #pragma unroll
                for (int dch = 0; dch < 4; ++dch) {
                    bf16x8 kf = *(const bf16x8*)&Ks[(kt*16 + c)*128 + (((dch*4 + g) ^ (c & 7)) * 8)];
                    sc[kt] = __builtin_amdgcn_mfma_f32_16x16x32_bf16(kf, qf[dch], sc[kt], 0, 0, 0);
                }
            }
        }
        float mx = -1e30f;
        #pragma unroll
        for (int kt = 0; kt < 4; ++kt)
            #pragma unroll
            for (int j = 0; j < 4; ++j) {
                const int key = tc + kt*16 + g*4 + j;
                const float s = (key <= q) ? sc[kt][j] * scale : -1e30f;
                mx = fmaxf(mx, s);
            }
        mx = fmaxf(mx, __shfl_xor(mx, 16));
        mx = fmaxf(mx, __shfl_xor(mx, 32));
        if (!__all(mx <= m_c + 8.f)) {
            const float mn = fmaxf(m_c, mx);
            const float corr = __expf(m_c - mn);
            l_c *= corr;
            m_c = mn;
            #pragma unroll
            for (int j = 0; j < 4; ++j) {
                const float cj = __shfl(corr, g*4 + j);
                #pragma unroll
                for (int ni = 0; ni < 8; ++ni) o[ni][j] *= cj;
            }
        }
        float ps = 0.f;
        #pragma unroll
        for (int kt = 0; kt < 4; ++kt) {
            float p[4];
            #pragma unroll
            for (int j = 0; j < 4; ++j) {
                const int key = tc + kt*16 + g*4 + j;
                const float s = (key <= q) ? sc[kt][j] * scale : -1e30f;
                p[j] = __expf(s - m_c);
                ps += p[j];
            }
            uint2 pk;
            pk.x = (unsigned int)f2bf(p[0]) | ((unsigned int)f2bf(p[1]) << 16);
            pk.y = (unsigned int)f2bf(p[2]) | ((unsigned int)f2bf(p[3]) << 16);
            const int byte = (c*128 + kt*32 + g*8) ^ ((c & 7) << 4);
            *(uint2*)(pw + byte) = pk;
        }
        ps += __shfl_xor(ps, 16);
        ps += __shfl_xor(ps, 32);
        l_c += ps;
        asm volatile("s_waitcnt lgkmcnt(0)" ::: "memory");
        __builtin_amdgcn_sched_barrier(0);
        #pragma unroll
        for (int kc = 0; kc < 2; ++kc) {
            if (tc + kc*32 <= qmaxw) {
                const int byte = (c*128 + kc*64 + g*16) ^ ((c & 7) << 4);
                bf16x8 pa = *(const bf16x8*)(pw + byte);
                #pragma unroll
                for (int ni = 0; ni < 8; ++ni) {
                    bf16x8 vf = *(const bf16x8*)&Vs[(ni*16 + c)*64 + (((kc*4 + g) ^ (c & 7)) * 8)];
                    o[ni] = __builtin_amdgcn_mfma_f32_16x16x32_bf16(pa, vf, o[ni], 0, 0, 0);
                }
            }
        }
        __syncthreads();
    }

    const int slot = ((b*NH + h) * 32 + qt) * 4 + ks;
    unsigned short* op = Opart + (size_t)slot * (64 * 128);
    #pragma unroll
    for (int ni = 0; ni < 8; ++ni)
        #pragma unroll
        for (int j = 0; j < 4; ++j)
            op[(size_t)(w*16 + g*4 + j) * 128 + ni*16 + c] = f2bf(o[ni][j]);
    if (lane < 16) {
        Ml[(size_t)slot * 128 +      w*16 + lane] = m_c;
        Ml[(size_t)slot * 128 + 64 + w*16 + lane] = l_c;
    }
}

// ------------- combine KV-split bf16 partials (4 slots) -> bf16 ctx ---------
__global__ __launch_bounds__(256) void k_attn_reduce(const unsigned short* __restrict__ Opart,
                                                     const float* __restrict__ Ml,
                                                     unsigned short* __restrict__ Ob) {
    const int qt = blockIdx.x, h = blockIdx.y, b = blockIdx.z;
    const int slot0 = ((b*NH + h) * 32 + qt) * 4;
    const int row = threadIdx.x >> 2;
    const int c0 = (threadIdx.x & 3) * 32;
    float M = -1e30f;
    #pragma unroll
    for (int s = 0; s < 4; ++s)
        M = fmaxf(M, Ml[(size_t)(slot0 + s) * 128 + row]);
    float L = 0.f;
    float wgt[4];
    #pragma unroll
    for (int s = 0; s < 4; ++s) {
        wgt[s] = __expf(Ml[(size_t)(slot0 + s) * 128 + row] - M);
        L += Ml[(size_t)(slot0 + s) * 128 + 64 + row] * wgt[s];
    }
    float acc[32];
    #pragma unroll
    for (int k = 0; k < 32; ++k) acc[k] = 0.f;
    #pragma unroll
    for (int s = 0; s < 4; ++s) {
        const unsigned short* op = Opart + ((size_t)(slot0 + s) * 64 + row) * 128 + c0;
        #pragma unroll
        for (int q4 = 0; q4 < 4; ++q4) {
            uint4 u = ((const uint4*)op)[q4];
            const unsigned int* pu = (const unsigned int*)&u;
            #pragma unroll
            for (int k = 0; k < 4; ++k) {
                acc[q4*8 + 2*k]     += bf2f(pu[k] & 0xffffu) * wgt[s];
                acc[q4*8 + 2*k + 1] += bf2f(pu[k] >> 16)     * wgt[s];
            }
        }
    }
    const float inv = 1.0f / L;
    unsigned short* orow = Ob + (size_t)(b*SEQ + qt*64 + row) * EMB + h*HD + c0;
    #pragma unroll
    for (int q4 = 0; q4 < 8; ++q4) {
        ushort4 u;
        u.x = f2bf(acc[q4*4+0] * inv); u.y = f2bf(acc[q4*4+1] * inv);
        u.z = f2bf(acc[q4*4+2] * inv); u.w = f2bf(acc[q4*4+3] * inv);
        ((ushort4*)orow)[q4] = u;
    }
}

// ------- row LayerNorm over 2048: x = X0+X1 (bf16) + bias (+resF f32 | resB bf16)
__global__ __launch_bounds__(256) void k_lnb(const unsigned short* __restrict__ X0,
                                             const unsigned short* __restrict__ X1,
                                             const float* __restrict__ bias,
                                             const float* __restrict__ resF,
                                             const unsigned short* __restrict__ resB,
                                             const float* __restrict__ g,
                                             const float* __restrict__ be,
                                             float* __restrict__ Of32,
                                             unsigned short* __restrict__ Obf16) {
    const int row = blockIdx.x, t = threadIdx.x;
    float v[8];
    {
        uint4 a = ((const uint4*)(X0 + (size_t)row * EMB))[t];
        uint4 b = ((const uint4*)(X1 + (size_t)row * EMB))[t];
        const unsigned int* pa = (const unsigned int*)&a;
        const unsigned int* pb = (const unsigned int*)&b;
        #pragma unroll
        for (int i = 0; i < 4; ++i) {
            v[2*i]   = bf2f(pa[i] & 0xffffu) + bf2f(pb[i] & 0xffffu);
            v[2*i+1] = bf2f(pa[i] >> 16)     + bf2f(pb[i] >> 16);
        }
    }
    {
        float4 b0 = ((const float4*)bias)[t*2], b1 = ((const float4*)bias)[t*2+1];
        v[0] += b0.x; v[1] += b0.y; v[2] += b0.z; v[3] += b0.w;
        v[4] += b1.x; v[5] += b1.y; v[6] += b1.z; v[7] += b1.w;
    }
    if (resF) {
        float4 r0 = ((const float4*)(resF + (size_t)row * EMB))[t*2];
        float4 r1 = ((const float4*)(resF + (size_t)row * EMB))[t*2+1];
        v[0] += r0.x; v[1] += r0.y; v[2] += r0.z; v[3] += r0.w;
        v[4] += r1.x; v[5] += r1.y; v[6] += r1.z; v[7] += r1.w;
    }
    if (resB) {
        uint4 r = ((const uint4*)(resB + (size_t)row * EMB))[t];
        const unsigned int* pr = (const unsigned int*)&r;
        #pragma unroll
        for (int i = 0; i < 4; ++i) {
            v[2*i]   += bf2f(pr[i] & 0xffffu);
            v[2*i+1] += bf2f(pr[i] >> 16);
        }
    }
    float s = 0.f, ss = 0.f;
    #pragma unroll
    for (int i = 0; i < 8; ++i) { s += v[i]; ss += v[i]*v[i]; }
    #pragma unroll
    for (int o = 32; o; o >>= 1) { s += __shfl_xor(s, o); ss += __shfl_xor(ss, o); }
    __shared__ float red[2][4];
    const int lane = t & 63, wid = t >> 6;
    if (lane == 0) { red[0][wid] = s; red[1][wid] = ss; }
    __syncthreads();
    s  = red[0][0] + red[0][1] + red[0][2] + red[0][3];
    ss = red[1][0] + red[1][1] + red[1][2] + red[1][3];
    const float mu = s * (1.0f / EMB);
    const float var = ss * (1.0f / EMB) - mu * mu;
    const float rs = rsqrtf(var + 1e-5f);
    float y[8];
    {
        float4 g0 = ((const float4*)g)[t*2],  g1v = ((const float4*)g)[t*2+1];
        float4 e0 = ((const float4*)be)[t*2], e1 = ((const float4*)be)[t*2+1];
        const float* pg0 = (const float*)&g0; const float* pg1 = (const float*)&g1v;
        const float* pe0 = (const float*)&e0; const float* pe1 = (const float*)&e1;
        #pragma unroll
        for (int i = 0; i < 4; ++i) {
            y[i]   = (v[i]   - mu) * rs * pg0[i] + pe0[i];
            y[i+4] = (v[i+4] - mu) * rs * pg1[i] + pe1[i];
        }
    }
    if (Of32) {
        float4 o0, o1;
        o0.x = y[0]; o0.y = y[1]; o0.z = y[2]; o0.w = y[3];
        o1.x = y[4]; o1.y = y[5]; o1.z = y[6]; o1.w = y[7];
        ((float4*)(Of32 + (size_t)row * EMB))[t*2]   = o0;
        ((float4*)(Of32 + (size_t)row * EMB))[t*2+1] = o1;
    }
    if (Obf16) {
        uint4 u;
        unsigned int* pu = (unsigned int*)&u;
        #pragma unroll
        for (int i = 0; i < 4; ++i)
            pu[i] = (unsigned int)f2bf(y[2*i]) | ((unsigned int)f2bf(y[2*i+1]) << 16);
        ((uint4*)(Obf16 + (size_t)row * EMB))[t] = u;
    }
}

extern "C" void kernel_launch(void* const* d_in, const int* in_sizes, int n_in,
                              void* d_out, int out_size, void* d_ws, size_t ws_size,
                              hipStream_t stream) {
    const float* emb = (const float*)d_in[0];
    const float* Wq  = (const float*)d_in[1];  const float* bq  = (const float*)d_in[2];
    const float* Wk  = (const float*)d_in[3];  const float* bk  = (const float*)d_in[4];
    const float* Wv  = (const float*)d_in[5];  const float* bv  = (const float*)d_in[6];
    const float* Wfc = (const float*)d_in[7];  const float* bfc = (const float*)d_in[8];
    const float* g1  = (const float*)d_in[9];  const float* be1 = (const float*)d_in[10];
    const float* W1  = (const float*)d_in[11]; const float* b1  = (const float*)d_in[12];
    const float* W2  = (const float*)d_in[13]; const float* b2  = (const float*)d_in[14];
    const float* g2  = (const float*)d_in[15]; const float* be2 = (const float*)d_in[16];

    // workspace layout (MiB offsets, lifetime-audited):
    //  [0,16)    aB: emb bf16 -> ctx bf16
    //  [16,32)   ln1B (after attn)
    //  [32,64)   WtB transposed weight (serial); [32,34) Ml during attn
    //  [64,128)  hB (W1 out); [64,80)/[80,96)/[96,112) Qb/Kb/VTb during attn
    //  [112,176) Opart bf16 (64 MiB) during attention only
    //  [176,208) pVT bf16 (V split-K partials, before attn) / pA+pB (after attn)
    //  [236,237) bias4 (bq||bk)
    char* ws = (char*)d_ws;
    unsigned short* aB   = (unsigned short*)(ws + (size_t)  0 * (1u<<20));
    unsigned short* ln1B = (unsigned short*)(ws + (size_t) 16 * (1u<<20));
    unsigned short* WtB  = (unsigned short*)(ws + (size_t) 32 * (1u<<20));
    float*          Ml   = (float*)         (ws + (size_t) 32 * (1u<<20));
    unsigned short* hB   = (unsigned short*)(ws + (size_t) 64 * (1u<<20));
    unsigned short* Qb   = (unsigned short*)(ws + (size_t) 64 * (1u<<20));
    unsigned short* Kb   = (unsigned short*)(ws + (size_t) 80 * (1u<<20));
    unsigned short* VTb  = (unsigned short*)(ws + (size_t) 96 * (1u<<20));
    unsigned short* Opart= (unsigned short*)(ws + (size_t)112 * (1u<<20));
    unsigned short* pA   = (unsigned short*)(ws + (size_t)176 * (1u<<20));
    unsigned short* pVT  = (unsigned short*)(ws + (size_t)176 * (1u<<20));
    float*          bias4= (float*)         (ws + (size_t)236 * (1u<<20));

    const dim3 blk(256);
    const dim3 blk2(512);
    const int n4 = MTOK * EMB / 4;
    const size_t PVT = (size_t)MTOK * EMB;   // one V-partial: 8.4M elems (16 MiB)

    // embeddings -> bf16; assemble fused QK bias (bq || bk)
    k_conv<<<dim3(n4 / 256), blk, 0, stream>>>(emb, aB, n4);
    hipMemcpyAsync(bias4,       bq, EMB*sizeof(float), hipMemcpyDeviceToDevice, stream);
    hipMemcpyAsync(bias4 + EMB, bk, EMB*sizeof(float), hipMemcpyDeviceToDevice, stream);

    // fused QK (N=4096, grid 512 balanced) + V split-K x2 (grid 512 balanced)
    k_transconv<<<dim3(EMB/32, EMB/32), blk, 0, stream>>>(Wq, WtB,             EMB, EMB);
    k_transconv<<<dim3(EMB/32, EMB/32), blk, 0, stream>>>(Wk, WtB + EMB*EMB,   EMB, EMB);
    k_transconv<<<dim3(EMB/32, EMB/32), blk, 0, stream>>>(Wv, WtB + 2*EMB*EMB, EMB, EMB);
    k_gemm5<7,1><<<dim3((MTOK/256)*(2*EMB/128)), blk2, 0, stream>>>(
        aB, WtB, bias4, Qb, Kb, MTOK, 2*EMB, EMB, EMB);
    k_gemm5<8,2><<<dim3((MTOK/256)*(EMB/128)*2), blk2, 0, stream>>>(
        aB, WtB + 2*EMB*EMB, nullptr, pVT, nullptr, MTOK, EMB, EMB/2, EMB);
    k_vcomb<<<dim3((int)(PVT/8/256)), blk, 0, stream>>>(pVT, pVT + PVT, bv, VTb);

    // KV-split MFMA flash attention -> bf16 partials -> ctx bf16 (overwrites aB)
    k_attn_part<<<dim3(4096), blk, 0, stream>>>(Qb, Kb, VTb, Opart, Ml);
    k_attn_reduce<<<dim3(SEQ/64, NH, BATCH), blk, 0, stream>>>(Opart, Ml, aB);

    // Wfc split-K x2 -> pA/pB bf16; LN1 fuses +bfc+emb -> ln1B only
    k_transconv<<<dim3(EMB/32, EMB/32), blk, 0, stream>>>(Wfc, WtB, EMB, EMB);
    k_gemm5<5,2><<<dim3((MTOK/256)*(EMB/128)*2), blk2, 0, stream>>>(
        aB, WtB, nullptr, pA, nullptr, MTOK, EMB, EMB/2, EMB);
    k_lnb<<<dim3(MTOK), blk, 0, stream>>>(pA, pA + (size_t)MTOK*EMB, bfc, emb, nullptr,
                                          g1, be1, nullptr, ln1B);

    // h = gelu(ln1 @ W1 + b1) -> hB
    k_transconv<<<dim3(4*EMB/32, EMB/32), blk, 0, stream>>>(W1, WtB, EMB, 4*EMB);
    k_gemm5<2,1><<<dim3((MTOK/256)*(4*EMB/128)), blk2, 0, stream>>>(
        ln1B, WtB, b1, hB, nullptr, MTOK, 4*EMB, EMB, EMB);

    // W2 split-K x2 -> pA/pB bf16; LN2 fuses +b2+ln1B -> d_out (f32)
    k_transconv<<<dim3(EMB/32, (4*EMB)/32), blk, 0, stream>>>(W2, WtB, 4*EMB, EMB);
    k_gemm5<5,2><<<dim3((MTOK/256)*(EMB/128)*2), blk2, 0, stream>>>(
        hB, WtB, nullptr, pA, nullptr, MTOK, EMB, 2*EMB, 4*EMB);
    k_lnb<<<dim3(MTOK), blk, 0, stream>>>(pA, pA + (size_t)MTOK*EMB, b2, nullptr, ln1B,
                                          g2, be2, (float*)d_out, nullptr);
}